// Round 1
// baseline (2997.000 us; speedup 1.0000x reference)
//
#include <hip/hip_runtime.h>

#define D_MODEL 1024
#define NHEADS 16
#define DKH 64
#define BATCH 4
#define SEQ 2048
#define MROWS (BATCH*SEQ)                 // 8192
#define BSD ((size_t)MROWS * D_MODEL)     // 8388608 floats per buffer

// C[m,n] = sum_k A[m,k] * W[n,k] + bias[n]
// A: (M x K) row-major.  W: (N x K) row-major (torch Linear weight layout).
// headSplit=1: write C in (B, H, S, DKH) layout for attention consumption.
__global__ __launch_bounds__(256) void gemm_nt_f32(
    const float* __restrict__ A, const float* __restrict__ W,
    const float* __restrict__ bias, float* __restrict__ C,
    int K, int N, int headSplit)
{
    __shared__ __align__(16) float As[16][68];
    __shared__ __align__(16) float Bs[16][68];
    const int t  = threadIdx.x;
    const int m0 = blockIdx.y << 6;
    const int n0 = blockIdx.x << 6;
    const int lr = t >> 2;            // 0..63 row of tile to stage
    const int lc = (t & 3) << 2;      // k offset 0,4,8,12
    const int tm = (t >> 4) << 2;     // 0..60 output row group
    const int tn = (t & 15) << 2;     // 0..60 output col group
    const float* Ap = A + (size_t)(m0 + lr) * K + lc;
    const float* Wp = W + (size_t)(n0 + lr) * K + lc;
    float acc[4][4] = {};
    for (int k0 = 0; k0 < K; k0 += 16) {
        const float4 av = *(const float4*)(Ap + k0);
        const float4 wv = *(const float4*)(Wp + k0);
        As[lc+0][lr] = av.x; As[lc+1][lr] = av.y; As[lc+2][lr] = av.z; As[lc+3][lr] = av.w;
        Bs[lc+0][lr] = wv.x; Bs[lc+1][lr] = wv.y; Bs[lc+2][lr] = wv.z; Bs[lc+3][lr] = wv.w;
        __syncthreads();
        #pragma unroll
        for (int kk = 0; kk < 16; ++kk) {
            const float4 a4 = *(const float4*)&As[kk][tm];
            const float4 b4 = *(const float4*)&Bs[kk][tn];
            const float a[4] = {a4.x, a4.y, a4.z, a4.w};
            const float b[4] = {b4.x, b4.y, b4.z, b4.w};
            #pragma unroll
            for (int i = 0; i < 4; ++i)
                #pragma unroll
                for (int j = 0; j < 4; ++j)
                    acc[i][j] += a[i] * b[j];
        }
        __syncthreads();
    }
    #pragma unroll
    for (int i = 0; i < 4; ++i) {
        const int m = m0 + tm + i;
        #pragma unroll
        for (int j = 0; j < 4; ++j) {
            const int n = n0 + tn + j;
            const float v = acc[i][j] + bias[n];
            if (headSplit) {
                // (b, h, s, dk) with b = m>>11, s = m&2047, h = n>>6, dk = n&63
                const size_t idx = (((size_t)((m >> 11) * NHEADS + (n >> 6)) << 11)
                                    + (size_t)(m & 2047)) * DKH + (n & 63);
                C[idx] = v;
            } else {
                C[(size_t)m * N + n] = v;
            }
        }
    }
}

// Flash attention, fp32. Q,K,V in (B*H, S, DKH) layout. O written (B, S, D_MODEL).
// Block: 256 threads = 64 q-rows x 4 lane-quad. Each thread owns one q-row and
// 16 interleaved k-columns (kc = kk*4 + cseg) + 16 output dims (cseg*16..+15).
__global__ __launch_bounds__(256) void attn_f32(
    const float* __restrict__ Q, const float* __restrict__ Kg,
    const float* __restrict__ V, float* __restrict__ O)
{
    __shared__ __align__(16) float Ks[64][68];
    __shared__ __align__(16) float Vs[64][68];
    __shared__ __align__(16) float Ps[64][68];
    const int t    = threadIdx.x;
    const int bh   = blockIdx.y;        // 0..63
    const int q0   = blockIdx.x << 6;
    const int r    = t >> 2;            // q-row within tile
    const int cseg = t & 3;
    const int lc4  = cseg << 4;         // 0,16,32,48

    // Q row into registers, pre-scaled by 1/sqrt(64)
    float qreg[64];
    {
        const float* Qp = Q + ((size_t)bh * SEQ + q0 + r) * DKH;
        #pragma unroll
        for (int i = 0; i < 16; ++i) {
            const float4 qv = *(const float4*)(Qp + i * 4);
            qreg[i*4+0] = qv.x * 0.125f;
            qreg[i*4+1] = qv.y * 0.125f;
            qreg[i*4+2] = qv.z * 0.125f;
            qreg[i*4+3] = qv.w * 0.125f;
        }
    }

    float m_r = -1e30f, l_r = 0.f;
    float acc[16] = {};

    for (int kt = 0; kt < SEQ / 64; ++kt) {
        const float* Kp = Kg + ((size_t)bh * SEQ + (kt << 6) + r) * DKH + lc4;
        const float* Vp = V  + ((size_t)bh * SEQ + (kt << 6) + r) * DKH + lc4;
        __syncthreads();   // previous tile fully consumed before overwrite
        #pragma unroll
        for (int i = 0; i < 4; ++i) {
            const float4 kv = *(const float4*)(Kp + i * 4);
            Ks[r][lc4 + i*4 + 0] = kv.x; Ks[r][lc4 + i*4 + 1] = kv.y;
            Ks[r][lc4 + i*4 + 2] = kv.z; Ks[r][lc4 + i*4 + 3] = kv.w;
            const float4 vv = *(const float4*)(Vp + i * 4);
            Vs[r][lc4 + i*4 + 0] = vv.x; Vs[r][lc4 + i*4 + 1] = vv.y;
            Vs[r][lc4 + i*4 + 2] = vv.z; Vs[r][lc4 + i*4 + 3] = vv.w;
        }
        __syncthreads();

        // scores for this thread's 16 k-columns (interleaved: kc = kk*4+cseg)
        float p[16];
        #pragma unroll
        for (int kk = 0; kk < 16; ++kk) {
            const int kc = (kk << 2) + cseg;
            float s = 0.f;
            #pragma unroll
            for (int d0 = 0; d0 < 64; d0 += 4) {
                const float4 kv = *(const float4*)&Ks[kc][d0];
                s += qreg[d0+0] * kv.x + qreg[d0+1] * kv.y
                   + qreg[d0+2] * kv.z + qreg[d0+3] * kv.w;
            }
            p[kk] = s;
        }

        // online softmax (row spread across 4 consecutive lanes)
        float tmax = p[0];
        #pragma unroll
        for (int kk = 1; kk < 16; ++kk) tmax = fmaxf(tmax, p[kk]);
        tmax = fmaxf(tmax, __shfl_xor(tmax, 1));
        tmax = fmaxf(tmax, __shfl_xor(tmax, 2));
        const float m_new   = fmaxf(m_r, tmax);
        const float rescale = __expf(m_r - m_new);
        float psum = 0.f;
        #pragma unroll
        for (int kk = 0; kk < 16; ++kk) { p[kk] = __expf(p[kk] - m_new); psum += p[kk]; }
        psum += __shfl_xor(psum, 1);
        psum += __shfl_xor(psum, 2);
        l_r = l_r * rescale + psum;
        m_r = m_new;
        #pragma unroll
        for (int dd = 0; dd < 16; ++dd) acc[dd] *= rescale;

        // publish p to LDS (only this wave's quad reads row r -> no barrier needed)
        #pragma unroll
        for (int kk = 0; kk < 16; ++kk) Ps[r][(kk << 2) + cseg] = p[kk];

        // PV: accumulate this thread's 16 output dims over the 64 keys
        #pragma unroll
        for (int k = 0; k < 64; ++k) {
            const float pv = Ps[r][k];
            const float4 v0 = *(const float4*)&Vs[k][lc4 + 0];
            const float4 v1 = *(const float4*)&Vs[k][lc4 + 4];
            const float4 v2 = *(const float4*)&Vs[k][lc4 + 8];
            const float4 v3 = *(const float4*)&Vs[k][lc4 + 12];
            acc[0]  += pv * v0.x; acc[1]  += pv * v0.y; acc[2]  += pv * v0.z; acc[3]  += pv * v0.w;
            acc[4]  += pv * v1.x; acc[5]  += pv * v1.y; acc[6]  += pv * v1.z; acc[7]  += pv * v1.w;
            acc[8]  += pv * v2.x; acc[9]  += pv * v2.y; acc[10] += pv * v2.z; acc[11] += pv * v2.w;
            acc[12] += pv * v3.x; acc[13] += pv * v3.y; acc[14] += pv * v3.z; acc[15] += pv * v3.w;
        }
    }

    const float inv = 1.f / l_r;
    const int b = bh >> 4, h = bh & 15;
    float* Op = O + ((size_t)b * SEQ + q0 + r) * D_MODEL + h * DKH + lc4;
    #pragma unroll
    for (int dd = 0; dd < 16; ++dd) Op[dd] = acc[dd] * inv;
}

extern "C" void kernel_launch(void* const* d_in, const int* in_sizes, int n_in,
                              void* d_out, int out_size, void* d_ws, size_t ws_size,
                              hipStream_t stream) {
    const float* q_in = (const float*)d_in[0];
    const float* k_in = (const float*)d_in[1];
    const float* v_in = (const float*)d_in[2];
    const float* w_q  = (const float*)d_in[3];
    const float* b_q  = (const float*)d_in[4];
    const float* w_k  = (const float*)d_in[5];
    const float* b_k  = (const float*)d_in[6];
    const float* w_v  = (const float*)d_in[7];
    const float* b_v  = (const float*)d_in[8];
    const float* w_o  = (const float*)d_in[9];
    const float* b_o  = (const float*)d_in[10];
    float* out = (float*)d_out;

    float* ws = (float*)d_ws;
    float* Qb = ws;            // (B*H, S, 64)
    float* Kb = ws + BSD;
    float* Vb = ws + 2 * BSD;
    float* Ab = ws + 3 * BSD;  // attention output, (B, S, D_MODEL)

    dim3 blk(256);
    dim3 gg(D_MODEL / 64, MROWS / 64);   // (16, 128)
    gemm_nt_f32<<<gg, blk, 0, stream>>>(q_in, w_q, b_q, Qb, D_MODEL, D_MODEL, 1);
    gemm_nt_f32<<<gg, blk, 0, stream>>>(k_in, w_k, b_k, Kb, D_MODEL, D_MODEL, 1);
    gemm_nt_f32<<<gg, blk, 0, stream>>>(v_in, w_v, b_v, Vb, D_MODEL, D_MODEL, 1);

    dim3 ga(SEQ / 64, BATCH * NHEADS);   // (32, 64)
    attn_f32<<<ga, blk, 0, stream>>>(Qb, Kb, Vb, Ab);

    gemm_nt_f32<<<gg, blk, 0, stream>>>(Ab, w_o, b_o, out, D_MODEL, D_MODEL, 0);
}

// Round 2
// 414.817 us; speedup vs baseline: 7.2249x; 7.2249x over previous
//
#include <hip/hip_runtime.h>
#include <hip/hip_bf16.h>

#define D_MODEL 1024
#define NHEADS 16
#define DKH 64
#define BATCH 4
#define SEQ 2048
#define MROWS (BATCH*SEQ)                 // 8192
#define BSD ((size_t)MROWS * D_MODEL)     // 8388608 elements per (B,S,D) buffer

typedef __attribute__((ext_vector_type(8))) short   s16x8;
typedef __attribute__((ext_vector_type(8))) __bf16  bf16x8;
typedef __attribute__((ext_vector_type(4))) float   f32x4;

__device__ inline short f2bf(float f) {
    __hip_bfloat16 h = __float2bfloat16(f);   // RNE
    short s; __builtin_memcpy(&s, &h, 2); return s;
}

// ---------------------------------------------------------------------------
// GEMM: C[m,n] = sum_k A[m,k] * W[n,k] + bias[n]
// AMODE 0: A fp32 (convert to bf16 while staging); AMODE 1: A already bf16.
// W always fp32 (converted while staging).
// OMODE 1: out bf16, head-split (B,H,S,DKH), value scaled by `scale`.
// OMODE 0: out fp32, flat (M, N).
// Tile 128x128, BK=64, 4 waves each computing 64x64 via 16x16x32 MFMA.
// ---------------------------------------------------------------------------
template<int AMODE, int OMODE>
__global__ __launch_bounds__(256, 2) void gemm_bt(
    const void* __restrict__ Ain, const float* __restrict__ W,
    const float* __restrict__ bias, void* __restrict__ Cout, float scale)
{
    __shared__ __align__(16) short As[128 * 64];
    __shared__ __align__(16) short Bs[128 * 64];
    const int t   = threadIdx.x;
    const int l   = t & 63;
    const int wid = t >> 6;
    const int g   = l >> 4, r16 = l & 15;
    const int wm  = wid >> 1, wn = wid & 1;
    const int m0  = blockIdx.y * 128, n0 = blockIdx.x * 128;
    const int srow = t >> 3;          // 0..31
    const int scol = (t & 7) * 8;     // element offset within BK=64

    f32x4 acc[4][4];
    #pragma unroll
    for (int mi = 0; mi < 4; ++mi)
        #pragma unroll
        for (int ni = 0; ni < 4; ++ni)
            acc[mi][ni] = (f32x4)0.0f;

    for (int k0 = 0; k0 < D_MODEL; k0 += 64) {
        #pragma unroll
        for (int p = 0; p < 4; ++p) {
            const int row = srow + p * 32;
            s16x8 av, bv;
            if (AMODE == 0) {
                const float* ap = (const float*)Ain + (size_t)(m0 + row) * D_MODEL + k0 + scol;
                const float4 a0 = *(const float4*)(ap);
                const float4 a1 = *(const float4*)(ap + 4);
                av[0]=f2bf(a0.x); av[1]=f2bf(a0.y); av[2]=f2bf(a0.z); av[3]=f2bf(a0.w);
                av[4]=f2bf(a1.x); av[5]=f2bf(a1.y); av[6]=f2bf(a1.z); av[7]=f2bf(a1.w);
            } else {
                av = *(const s16x8*)((const short*)Ain + (size_t)(m0 + row) * D_MODEL + k0 + scol);
            }
            {
                const float* wp = W + (size_t)(n0 + row) * D_MODEL + k0 + scol;
                const float4 w0 = *(const float4*)(wp);
                const float4 w1 = *(const float4*)(wp + 4);
                bv[0]=f2bf(w0.x); bv[1]=f2bf(w0.y); bv[2]=f2bf(w0.z); bv[3]=f2bf(w0.w);
                bv[4]=f2bf(w1.x); bv[5]=f2bf(w1.y); bv[6]=f2bf(w1.z); bv[7]=f2bf(w1.w);
            }
            *(s16x8*)&As[row * 64 + scol] = av;
            *(s16x8*)&Bs[row * 64 + scol] = bv;
        }
        __syncthreads();
        #pragma unroll
        for (int kc = 0; kc < 2; ++kc) {
            bf16x8 a[4], b[4];
            #pragma unroll
            for (int mi = 0; mi < 4; ++mi)
                a[mi] = *(const bf16x8*)&As[(wm * 64 + mi * 16 + r16) * 64 + kc * 32 + g * 8];
            #pragma unroll
            for (int ni = 0; ni < 4; ++ni)
                b[ni] = *(const bf16x8*)&Bs[(wn * 64 + ni * 16 + r16) * 64 + kc * 32 + g * 8];
            #pragma unroll
            for (int mi = 0; mi < 4; ++mi)
                #pragma unroll
                for (int ni = 0; ni < 4; ++ni)
                    acc[mi][ni] = __builtin_amdgcn_mfma_f32_16x16x32_bf16(a[mi], b[ni], acc[mi][ni], 0, 0, 0);
        }
        __syncthreads();
    }

    #pragma unroll
    for (int mi = 0; mi < 4; ++mi)
        #pragma unroll
        for (int ni = 0; ni < 4; ++ni)
            #pragma unroll
            for (int j = 0; j < 4; ++j) {
                const int m = m0 + wm * 64 + mi * 16 + g * 4 + j;
                const int n = n0 + wn * 64 + ni * 16 + r16;
                float v = acc[mi][ni][j] + bias[n];
                if (OMODE == 1) {
                    v *= scale;
                    const size_t idx = (((size_t)((m >> 11) * NHEADS + (n >> 6)) << 11)
                                        + (size_t)(m & 2047)) * DKH + (n & 63);
                    ((short*)Cout)[idx] = f2bf(v);
                } else {
                    ((float*)Cout)[(size_t)m * D_MODEL + n] = v;
                }
            }
}

// ---------------------------------------------------------------------------
// V transpose: (BH, S, 64) bf16 -> (BH, 64, S) bf16, 64x64 LDS tiles
// ---------------------------------------------------------------------------
__global__ __launch_bounds__(256) void transpose_v(
    const short* __restrict__ Vb, short* __restrict__ Vt)
{
    __shared__ __align__(16) short T[64][72];
    const int t  = threadIdx.x;
    const int bh = blockIdx.y;
    const int s0 = blockIdx.x * 64;
    const int row = t >> 2, cb = (t & 3) * 16;
    const short* src = Vb + ((size_t)bh * SEQ + s0 + row) * DKH + cb;
    *(s16x8*)&T[row][cb]     = *(const s16x8*)(src);
    *(s16x8*)&T[row][cb + 8] = *(const s16x8*)(src + 8);
    __syncthreads();
    const int d = t >> 2, sb = (t & 3) * 16;
    s16x8 o0, o1;
    #pragma unroll
    for (int j = 0; j < 8; ++j) { o0[j] = T[sb + j][d]; o1[j] = T[sb + 8 + j][d]; }
    short* dst = Vt + ((size_t)bh * DKH + d) * SEQ + s0 + sb;
    *(s16x8*)(dst)     = o0;
    *(s16x8*)(dst + 8) = o1;
}

// ---------------------------------------------------------------------------
// Flash attention, bf16 MFMA. Q pre-scaled by 0.125 at projection.
// Q,K: (BH, S, 64) bf16. Vt: (BH, 64, S) bf16. Out Ab: (B, S, D_MODEL) bf16.
// Block: 4 waves x 32 q-rows = 128 q-rows; KV tile = 64 keys.
// ---------------------------------------------------------------------------
__global__ __launch_bounds__(256, 2) void attn_mfma(
    const short* __restrict__ Qg, const short* __restrict__ Kg,
    const short* __restrict__ Vtg, short* __restrict__ Ab)
{
    __shared__ __align__(16) short Qs[128 * 72];
    __shared__ __align__(16) short Ks[64 * 72];
    __shared__ __align__(16) short Vts[64 * 72];
    __shared__ __align__(16) short Ps[4][32 * 72];
    const int t   = threadIdx.x;
    const int l   = t & 63;
    const int wid = t >> 6;
    const int g   = l >> 4, r16 = l & 15;
    const int bh  = blockIdx.y, b = bh >> 4, h = bh & 15;
    const int q0  = blockIdx.x * 128;
    const int wq0 = wid * 32;
    const int srow = t >> 3, scol = (t & 7) * 8;

    // stage Q tile (128 x 64)
    #pragma unroll
    for (int p = 0; p < 4; ++p) {
        const int row = srow + p * 32;
        *(s16x8*)&Qs[row * 72 + scol] =
            *(const s16x8*)&Qg[((size_t)bh * SEQ + q0 + row) * DKH + scol];
    }
    __syncthreads();
    bf16x8 aq[2][2];
    #pragma unroll
    for (int mi = 0; mi < 2; ++mi)
        #pragma unroll
        for (int kc = 0; kc < 2; ++kc)
            aq[mi][kc] = *(const bf16x8*)&Qs[(wq0 + mi * 16 + r16) * 72 + kc * 32 + g * 8];

    f32x4 o_acc[2][4];
    float m_r[2][4], l_r[2][4];
    #pragma unroll
    for (int mi = 0; mi < 2; ++mi)
        #pragma unroll
        for (int nd = 0; nd < 4; ++nd) o_acc[mi][nd] = (f32x4)0.0f;
    #pragma unroll
    for (int mi = 0; mi < 2; ++mi)
        #pragma unroll
        for (int j = 0; j < 4; ++j) { m_r[mi][j] = -1e30f; l_r[mi][j] = 0.0f; }

    short* Pw = &Ps[wid][0];

    for (int kt = 0; kt < SEQ / 64; ++kt) {
        __syncthreads();
        #pragma unroll
        for (int p = 0; p < 2; ++p) {
            const int row = srow + p * 32;
            *(s16x8*)&Ks[row * 72 + scol] =
                *(const s16x8*)&Kg[((size_t)bh * SEQ + kt * 64 + row) * DKH + scol];
            *(s16x8*)&Vts[row * 72 + scol] =
                *(const s16x8*)&Vtg[((size_t)bh * DKH + row) * SEQ + kt * 64 + scol];
        }
        __syncthreads();

        // S = Q K^T (per wave: 32q x 64k)
        f32x4 s_acc[2][4];
        #pragma unroll
        for (int mi = 0; mi < 2; ++mi)
            #pragma unroll
            for (int nk = 0; nk < 4; ++nk) s_acc[mi][nk] = (f32x4)0.0f;
        #pragma unroll
        for (int kc = 0; kc < 2; ++kc) {
            bf16x8 bk[4];
            #pragma unroll
            for (int nk = 0; nk < 4; ++nk)
                bk[nk] = *(const bf16x8*)&Ks[(nk * 16 + r16) * 72 + kc * 32 + g * 8];
            #pragma unroll
            for (int mi = 0; mi < 2; ++mi)
                #pragma unroll
                for (int nk = 0; nk < 4; ++nk)
                    s_acc[mi][nk] = __builtin_amdgcn_mfma_f32_16x16x32_bf16(aq[mi][kc], bk[nk], s_acc[mi][nk], 0, 0, 0);
        }

        // online softmax; rows live in 16-lane groups (xor 1,2,4,8)
        #pragma unroll
        for (int mi = 0; mi < 2; ++mi)
            #pragma unroll
            for (int j = 0; j < 4; ++j) {
                float mx = fmaxf(fmaxf(s_acc[mi][0][j], s_acc[mi][1][j]),
                                 fmaxf(s_acc[mi][2][j], s_acc[mi][3][j]));
                mx = fmaxf(mx, __shfl_xor(mx, 1));
                mx = fmaxf(mx, __shfl_xor(mx, 2));
                mx = fmaxf(mx, __shfl_xor(mx, 4));
                mx = fmaxf(mx, __shfl_xor(mx, 8));
                const float mnew = fmaxf(m_r[mi][j], mx);
                const float resc = __expf(m_r[mi][j] - mnew);
                m_r[mi][j] = mnew;
                float sum = 0.0f;
                #pragma unroll
                for (int nk = 0; nk < 4; ++nk) {
                    const float pv = __expf(s_acc[mi][nk][j] - mnew);
                    s_acc[mi][nk][j] = pv;
                    sum += pv;
                }
                sum += __shfl_xor(sum, 1);
                sum += __shfl_xor(sum, 2);
                sum += __shfl_xor(sum, 4);
                sum += __shfl_xor(sum, 8);
                l_r[mi][j] = l_r[mi][j] * resc + sum;
                #pragma unroll
                for (int nd = 0; nd < 4; ++nd) o_acc[mi][nd][j] *= resc;
            }

        // publish P (bf16) to this wave's LDS region
        #pragma unroll
        for (int mi = 0; mi < 2; ++mi)
            #pragma unroll
            for (int nk = 0; nk < 4; ++nk)
                #pragma unroll
                for (int j = 0; j < 4; ++j)
                    Pw[(mi * 16 + g * 4 + j) * 72 + nk * 16 + r16] = f2bf(s_acc[mi][nk][j]);

        // O += P V  (per wave: 32q x 64d, K=64 keys)
        #pragma unroll
        for (int kc = 0; kc < 2; ++kc) {
            bf16x8 pa[2], bv[4];
            #pragma unroll
            for (int mi = 0; mi < 2; ++mi)
                pa[mi] = *(const bf16x8*)&Pw[(mi * 16 + r16) * 72 + kc * 32 + g * 8];
            #pragma unroll
            for (int nd = 0; nd < 4; ++nd)
                bv[nd] = *(const bf16x8*)&Vts[(nd * 16 + r16) * 72 + kc * 32 + g * 8];
            #pragma unroll
            for (int mi = 0; mi < 2; ++mi)
                #pragma unroll
                for (int nd = 0; nd < 4; ++nd)
                    o_acc[mi][nd] = __builtin_amdgcn_mfma_f32_16x16x32_bf16(pa[mi], bv[nd], o_acc[mi][nd], 0, 0, 0);
        }
    }

    // epilogue: normalize and write bf16 (B, S, D_MODEL)
    #pragma unroll
    for (int mi = 0; mi < 2; ++mi)
        #pragma unroll
        for (int j = 0; j < 4; ++j) {
            const float inv = 1.0f / l_r[mi][j];
            const int q = q0 + wq0 + mi * 16 + g * 4 + j;
            #pragma unroll
            for (int nd = 0; nd < 4; ++nd) {
                const int dglob = h * DKH + nd * 16 + r16;
                Ab[((size_t)b * SEQ + q) * D_MODEL + dglob] = f2bf(o_acc[mi][nd][j] * inv);
            }
        }
}

extern "C" void kernel_launch(void* const* d_in, const int* in_sizes, int n_in,
                              void* d_out, int out_size, void* d_ws, size_t ws_size,
                              hipStream_t stream) {
    const float* q_in = (const float*)d_in[0];
    const float* k_in = (const float*)d_in[1];
    const float* v_in = (const float*)d_in[2];
    const float* w_q  = (const float*)d_in[3];
    const float* b_q  = (const float*)d_in[4];
    const float* w_k  = (const float*)d_in[5];
    const float* b_k  = (const float*)d_in[6];
    const float* w_v  = (const float*)d_in[7];
    const float* b_v  = (const float*)d_in[8];
    const float* w_o  = (const float*)d_in[9];
    const float* b_o  = (const float*)d_in[10];
    float* out = (float*)d_out;

    short* ws = (short*)d_ws;
    short* Qb = ws;                 // (B*H, S, 64) bf16, pre-scaled by 0.125
    short* Kb = ws + BSD;           // (B*H, S, 64) bf16
    short* Vb = ws + 2 * BSD;       // (B*H, S, 64) bf16
    short* Vt = ws + 3 * BSD;       // (B*H, 64, S) bf16
    short* Ab = ws + 4 * BSD;       // (B, S, D_MODEL) bf16

    dim3 blk(256);
    dim3 gg(D_MODEL / 128, MROWS / 128);          // (8, 64)
    gemm_bt<0, 1><<<gg, blk, 0, stream>>>(q_in, w_q, b_q, Qb, 0.125f);
    gemm_bt<0, 1><<<gg, blk, 0, stream>>>(k_in, w_k, b_k, Kb, 1.0f);
    gemm_bt<0, 1><<<gg, blk, 0, stream>>>(v_in, w_v, b_v, Vb, 1.0f);

    transpose_v<<<dim3(SEQ / 64, BATCH * NHEADS), blk, 0, stream>>>(Vb, Vt);

    attn_mfma<<<dim3(SEQ / 128, BATCH * NHEADS), blk, 0, stream>>>(Qb, Kb, Vt, Ab);

    gemm_bt<1, 0><<<gg, blk, 0, stream>>>(Ab, w_o, b_o, out, 1.0f);
}

// Round 3
// 298.101 us; speedup vs baseline: 10.0536x; 1.3915x over previous
//
#include <hip/hip_runtime.h>
#include <hip/hip_bf16.h>

#define D_MODEL 1024
#define NHEADS 16
#define DKH 64
#define BATCH 4
#define SEQ 2048
#define MROWS (BATCH*SEQ)                 // 8192
#define BSD ((size_t)MROWS * D_MODEL)     // 8388608 elements
#define WSZ ((size_t)D_MODEL * D_MODEL)   // 1048576 elements
#define LOG2E 1.4426950408889634f

typedef __attribute__((ext_vector_type(8))) short   s16x8;
typedef __attribute__((ext_vector_type(8))) __bf16  bf16x8;
typedef __attribute__((ext_vector_type(4))) float   f32x4;

// RNE f32->bf16 for finite values (bit trick, no NaN path needed here)
__device__ inline unsigned bfround(float f) {
    unsigned u = __float_as_uint(f);
    return (u + 0x7FFFu + ((u >> 16) & 1u)) >> 16;
}
__device__ inline short f2bf(float f) { return (short)bfround(f); }

__device__ inline void gl_lds16(const void* g, void* l) {
    __builtin_amdgcn_global_load_lds(
        (const __attribute__((address_space(1))) unsigned*)g,
        (__attribute__((address_space(3))) unsigned*)l, 16, 0, 0);
}

// ---------------------------------------------------------------------------
// Elementwise f32 -> bf16 (n multiple of 2048, grid = n/2048)
// ---------------------------------------------------------------------------
__global__ __launch_bounds__(256) void cvt_f32_bf16(
    const float* __restrict__ in, short* __restrict__ out)
{
    const size_t i = ((size_t)blockIdx.x * 256 + threadIdx.x) * 8;
    const float4 a = *(const float4*)(in + i);
    const float4 b = *(const float4*)(in + i + 4);
    s16x8 v;
    v[0]=f2bf(a.x); v[1]=f2bf(a.y); v[2]=f2bf(a.z); v[3]=f2bf(a.w);
    v[4]=f2bf(b.x); v[5]=f2bf(b.y); v[6]=f2bf(b.z); v[7]=f2bf(b.w);
    *(s16x8*)(out + i) = v;
}

// ---------------------------------------------------------------------------
// GEMM (all bf16 in): C[m,n] = sum_k A[m,k]*W[n,k] + bias[n]
// m97 structure: 128x128 tile, BK=64, global_load_lds width 16, linear LDS.
// OMODE 1: bf16 out, head-split (B,H,S,DKH), scaled. OMODE 0: fp32 flat out.
// ---------------------------------------------------------------------------
template<int OMODE>
__global__ __launch_bounds__(256, 2) void gemm_bf16(
    const short* __restrict__ A, const short* __restrict__ W,
    const float* __restrict__ bias, void* __restrict__ Cout, float scale)
{
    __shared__ __align__(16) short As[128 * 64];
    __shared__ __align__(16) short Bs[128 * 64];
    const int t   = threadIdx.x;
    const int l   = t & 63;
    const int wid = t >> 6;
    const int g   = l >> 4, r16 = l & 15;
    const int wm  = wid >> 1, wn = wid & 1;
    const int m0  = blockIdx.y * 128, n0 = blockIdx.x * 128;
    const int srow = t >> 3;          // 0..31
    const int scol = (t & 7) * 8;     // element offset within BK=64

    f32x4 acc[4][4];
    #pragma unroll
    for (int mi = 0; mi < 4; ++mi)
        #pragma unroll
        for (int ni = 0; ni < 4; ++ni)
            acc[mi][ni] = (f32x4)0.0f;

    const short* Ap = A + (size_t)(m0 + srow) * D_MODEL + scol;
    const short* Wp = W + (size_t)(n0 + srow) * D_MODEL + scol;
    short* AsW = As + wid * 512;   // wave-uniform LDS base (lane*16B added by HW)
    short* BsW = Bs + wid * 512;

    for (int k0 = 0; k0 < D_MODEL; k0 += 64) {
        #pragma unroll
        for (int p = 0; p < 4; ++p) {
            gl_lds16(Ap + (size_t)p * 32 * D_MODEL + k0, AsW + p * 2048);
            gl_lds16(Wp + (size_t)p * 32 * D_MODEL + k0, BsW + p * 2048);
        }
        __syncthreads();            // drains vmcnt, LDS ready
        #pragma unroll
        for (int kc = 0; kc < 2; ++kc) {
            bf16x8 a[4], b[4];
            #pragma unroll
            for (int mi = 0; mi < 4; ++mi)
                a[mi] = *(const bf16x8*)&As[(wm * 64 + mi * 16 + r16) * 64 + kc * 32 + g * 8];
            #pragma unroll
            for (int ni = 0; ni < 4; ++ni)
                b[ni] = *(const bf16x8*)&Bs[(wn * 64 + ni * 16 + r16) * 64 + kc * 32 + g * 8];
            #pragma unroll
            for (int mi = 0; mi < 4; ++mi)
                #pragma unroll
                for (int ni = 0; ni < 4; ++ni)
                    acc[mi][ni] = __builtin_amdgcn_mfma_f32_16x16x32_bf16(a[mi], b[ni], acc[mi][ni], 0, 0, 0);
        }
        __syncthreads();
    }

    #pragma unroll
    for (int mi = 0; mi < 4; ++mi)
        #pragma unroll
        for (int ni = 0; ni < 4; ++ni)
            #pragma unroll
            for (int j = 0; j < 4; ++j) {
                const int m = m0 + wm * 64 + mi * 16 + g * 4 + j;
                const int n = n0 + wn * 64 + ni * 16 + r16;
                float v = acc[mi][ni][j] + bias[n];
                if (OMODE == 1) {
                    v *= scale;
                    const size_t idx = (((size_t)((m >> 11) * NHEADS + (n >> 6)) << 11)
                                        + (size_t)(m & 2047)) * DKH + (n & 63);
                    ((short*)Cout)[idx] = f2bf(v);
                } else {
                    ((float*)Cout)[(size_t)m * D_MODEL + n] = v;
                }
            }
}

// ---------------------------------------------------------------------------
// V transpose: (BH, S, 64) bf16 -> (BH, 64, S) bf16
// ---------------------------------------------------------------------------
__global__ __launch_bounds__(256) void transpose_v(
    const short* __restrict__ Vb, short* __restrict__ Vt)
{
    __shared__ __align__(16) short T[64][72];
    const int t  = threadIdx.x;
    const int bh = blockIdx.y;
    const int s0 = blockIdx.x * 64;
    const int row = t >> 2, cb = (t & 3) * 16;
    const short* src = Vb + ((size_t)bh * SEQ + s0 + row) * DKH + cb;
    *(s16x8*)&T[row][cb]     = *(const s16x8*)(src);
    *(s16x8*)&T[row][cb + 8] = *(const s16x8*)(src + 8);
    __syncthreads();
    const int d = t >> 2, sb = (t & 3) * 16;
    s16x8 o0, o1;
    #pragma unroll
    for (int j = 0; j < 8; ++j) { o0[j] = T[sb + j][d]; o1[j] = T[sb + 8 + j][d]; }
    short* dst = Vt + ((size_t)bh * DKH + d) * SEQ + s0 + sb;
    *(s16x8*)(dst)     = o0;
    *(s16x8*)(dst + 8) = o1;
}

// ---------------------------------------------------------------------------
// Flash attention, swapped-operand MFMA. Q pre-scaled by 0.125*log2(e).
// S^T = mfma(K, Q): lane-resident q column -> softmax state fully lane-local.
// O^T = mfma(V^T, P^T). Q,K: (BH,S,64) bf16; Vt: (BH,64,S) bf16.
// Block: 4 waves x 32 q = 128 q-rows; KV tile 64.
// ---------------------------------------------------------------------------
__global__ __launch_bounds__(256, 2) void attn_mfma(
    const short* __restrict__ Qg, const short* __restrict__ Kg,
    const short* __restrict__ Vtg, short* __restrict__ Ab)
{
    __shared__ __align__(16) short Qs[128 * 72];
    __shared__ __align__(16) short Ks[64 * 72];
    __shared__ __align__(16) short Vts[64 * 72];
    __shared__ __align__(16) short Ps[4][32 * 72];
    const int t   = threadIdx.x;
    const int l   = t & 63;
    const int wid = t >> 6;
    const int g   = l >> 4, r16 = l & 15;
    const int bh  = blockIdx.y, b = bh >> 4, h = bh & 15;
    const int q0  = blockIdx.x * 128;
    const int wq0 = wid * 32;
    const int srow = t >> 3, scol = (t & 7) * 8;   // Q staging
    const int kr = t >> 2, kcb = (t & 3) * 16;     // K/V staging

    // stage Q tile (128 x 64)
    #pragma unroll
    for (int p = 0; p < 4; ++p) {
        const int row = srow + p * 32;
        *(s16x8*)&Qs[row * 72 + scol] =
            *(const s16x8*)&Qg[((size_t)bh * SEQ + q0 + row) * DKH + scol];
    }
    const short* Kbase = Kg  + (size_t)bh * SEQ * DKH;
    const short* Vbase = Vtg + (size_t)bh * DKH * SEQ;
    // prefetch KV tile 0 into registers (T14: issue-early / write-late)
    s16x8 kpf0 = *(const s16x8*)&Kbase[(size_t)kr * DKH + kcb];
    s16x8 kpf1 = *(const s16x8*)&Kbase[(size_t)kr * DKH + kcb + 8];
    s16x8 vpf0 = *(const s16x8*)&Vbase[(size_t)kr * SEQ + kcb];
    s16x8 vpf1 = *(const s16x8*)&Vbase[(size_t)kr * SEQ + kcb + 8];
    __syncthreads();

    // hoist Q fragments (B-operand: lane holds col q = wq0+mi*16+r16)
    bf16x8 bq[2][2];
    #pragma unroll
    for (int mi = 0; mi < 2; ++mi)
        #pragma unroll
        for (int kc = 0; kc < 2; ++kc)
            bq[mi][kc] = *(const bf16x8*)&Qs[(wq0 + mi * 16 + r16) * 72 + kc * 32 + g * 8];

    f32x4 o_acc[4][2];                 // [nd][mi]: O^T rows d, cols q
    float m_r[2] = {-1e30f, -1e30f};
    float l_r[2] = {0.0f, 0.0f};
    #pragma unroll
    for (int nd = 0; nd < 4; ++nd)
        #pragma unroll
        for (int mi = 0; mi < 2; ++mi) o_acc[nd][mi] = (f32x4)0.0f;

    short* Pw = &Ps[wid][0];

    for (int kt = 0; kt < SEQ / 64; ++kt) {
        __syncthreads();               // all waves done reading previous K/V
        *(s16x8*)&Ks[kr * 72 + kcb]      = kpf0;
        *(s16x8*)&Ks[kr * 72 + kcb + 8]  = kpf1;
        *(s16x8*)&Vts[kr * 72 + kcb]     = vpf0;
        *(s16x8*)&Vts[kr * 72 + kcb + 8] = vpf1;
        __syncthreads();
        if (kt + 1 < SEQ / 64) {       // issue next-tile loads; land during compute
            kpf0 = *(const s16x8*)&Kbase[(size_t)((kt + 1) * 64 + kr) * DKH + kcb];
            kpf1 = *(const s16x8*)&Kbase[(size_t)((kt + 1) * 64 + kr) * DKH + kcb + 8];
            vpf0 = *(const s16x8*)&Vbase[(size_t)kr * SEQ + (kt + 1) * 64 + kcb];
            vpf1 = *(const s16x8*)&Vbase[(size_t)kr * SEQ + (kt + 1) * 64 + kcb + 8];
        }

        // S^T = K Q^T  (rows k = nk*16+g*4+j, col q = mi*16+r16)
        f32x4 sT[4][2];
        #pragma unroll
        for (int nk = 0; nk < 4; ++nk)
            #pragma unroll
            for (int mi = 0; mi < 2; ++mi) sT[nk][mi] = (f32x4)0.0f;
        #pragma unroll
        for (int kc = 0; kc < 2; ++kc) {
            bf16x8 ak[4];
            #pragma unroll
            for (int nk = 0; nk < 4; ++nk)
                ak[nk] = *(const bf16x8*)&Ks[(nk * 16 + r16) * 72 + kc * 32 + g * 8];
            #pragma unroll
            for (int nk = 0; nk < 4; ++nk)
                #pragma unroll
                for (int mi = 0; mi < 2; ++mi)
                    sT[nk][mi] = __builtin_amdgcn_mfma_f32_16x16x32_bf16(ak[nk], bq[mi][kc], sT[nk][mi], 0, 0, 0);
        }

        // lane-local online softmax (exp2 domain); cross-lane only over g (xor 16,32)
        #pragma unroll
        for (int mi = 0; mi < 2; ++mi) {
            float mx = -1e30f;
            #pragma unroll
            for (int nk = 0; nk < 4; ++nk)
                #pragma unroll
                for (int j = 0; j < 4; ++j) mx = fmaxf(mx, sT[nk][mi][j]);
            mx = fmaxf(mx, __shfl_xor(mx, 16));
            mx = fmaxf(mx, __shfl_xor(mx, 32));
            const float mnew = fmaxf(m_r[mi], mx);
            const float resc = __builtin_amdgcn_exp2f(m_r[mi] - mnew);
            m_r[mi] = mnew;
            float sum = 0.0f;
            #pragma unroll
            for (int nk = 0; nk < 4; ++nk)
                #pragma unroll
                for (int j = 0; j < 4; ++j) {
                    const float pv = __builtin_amdgcn_exp2f(sT[nk][mi][j] - mnew);
                    sT[nk][mi][j] = pv;
                    sum += pv;
                }
            sum += __shfl_xor(sum, 16);
            sum += __shfl_xor(sum, 32);
            l_r[mi] = l_r[mi] * resc + sum;
            #pragma unroll
            for (int nd = 0; nd < 4; ++nd)
                #pragma unroll
                for (int j = 0; j < 4; ++j) o_acc[nd][mi][j] *= resc;
        }

        // publish P[q][k] bf16 (packed b64 writes; per-wave region, no barrier)
        #pragma unroll
        for (int mi = 0; mi < 2; ++mi)
            #pragma unroll
            for (int nk = 0; nk < 4; ++nk) {
                uint2 w;
                w.x = bfround(sT[nk][mi][0]) | (bfround(sT[nk][mi][1]) << 16);
                w.y = bfround(sT[nk][mi][2]) | (bfround(sT[nk][mi][3]) << 16);
                *(uint2*)&Pw[(mi * 16 + r16) * 72 + nk * 16 + g * 4] = w;
            }

        // O^T += V^T P^T  (A = V^T rows d, B = P^T cols q)
        #pragma unroll
        for (int kc = 0; kc < 2; ++kc) {
            bf16x8 av[4], bp[2];
            #pragma unroll
            for (int nd = 0; nd < 4; ++nd)
                av[nd] = *(const bf16x8*)&Vts[(nd * 16 + r16) * 72 + kc * 32 + g * 8];
            #pragma unroll
            for (int mi = 0; mi < 2; ++mi)
                bp[mi] = *(const bf16x8*)&Pw[(mi * 16 + r16) * 72 + kc * 32 + g * 8];
            #pragma unroll
            for (int nd = 0; nd < 4; ++nd)
                #pragma unroll
                for (int mi = 0; mi < 2; ++mi)
                    o_acc[nd][mi] = __builtin_amdgcn_mfma_f32_16x16x32_bf16(av[nd], bp[mi], o_acc[nd][mi], 0, 0, 0);
        }
    }

    // epilogue: normalize (lane-local l) and write O (B,S,D) bf16, packed 8B
    #pragma unroll
    for (int mi = 0; mi < 2; ++mi) {
        const float inv = 1.0f / l_r[mi];
        const int q = q0 + wq0 + mi * 16 + r16;
        short* Op = Ab + ((size_t)b * SEQ + q) * D_MODEL + h * DKH;
        #pragma unroll
        for (int nd = 0; nd < 4; ++nd) {
            uint2 w;
            w.x = bfround(o_acc[nd][mi][0] * inv) | (bfround(o_acc[nd][mi][1] * inv) << 16);
            w.y = bfround(o_acc[nd][mi][2] * inv) | (bfround(o_acc[nd][mi][3] * inv) << 16);
            *(uint2*)&Op[nd * 16 + g * 4] = w;
        }
    }
}

extern "C" void kernel_launch(void* const* d_in, const int* in_sizes, int n_in,
                              void* d_out, int out_size, void* d_ws, size_t ws_size,
                              hipStream_t stream) {
    const float* q_in = (const float*)d_in[0];
    const float* k_in = (const float*)d_in[1];
    const float* v_in = (const float*)d_in[2];
    const float* w_q  = (const float*)d_in[3];
    const float* b_q  = (const float*)d_in[4];
    const float* w_k  = (const float*)d_in[5];
    const float* b_k  = (const float*)d_in[6];
    const float* w_v  = (const float*)d_in[7];
    const float* b_v  = (const float*)d_in[8];
    const float* w_o  = (const float*)d_in[9];
    const float* b_o  = (const float*)d_in[10];
    float* out = (float*)d_out;

    short* ws = (short*)d_ws;
    short* Qc  = ws;                          // bf16 copies of inputs
    short* Kc  = ws + BSD;
    short* Vc  = ws + 2 * BSD;
    short* Wq  = ws + 3 * BSD;
    short* Wk  = Wq + WSZ;
    short* Wv  = Wk + WSZ;
    short* Wo  = Wv + WSZ;
    short* Qb  = ws + 3 * BSD + 4 * WSZ;      // (B*H,S,64) bf16, scaled
    short* Kb  = Qb + BSD;
    short* Vb  = Kb + BSD;
    short* Vt  = Qc;                          // alias: Qc dead after Q-proj
    short* Ab  = Kc;                          // alias: Kc dead after K-proj

    dim3 blk(256);
    cvt_f32_bf16<<<dim3(BSD / 2048), blk, 0, stream>>>(q_in, Qc);
    cvt_f32_bf16<<<dim3(BSD / 2048), blk, 0, stream>>>(k_in, Kc);
    cvt_f32_bf16<<<dim3(BSD / 2048), blk, 0, stream>>>(v_in, Vc);
    cvt_f32_bf16<<<dim3(WSZ / 2048), blk, 0, stream>>>(w_q, Wq);
    cvt_f32_bf16<<<dim3(WSZ / 2048), blk, 0, stream>>>(w_k, Wk);
    cvt_f32_bf16<<<dim3(WSZ / 2048), blk, 0, stream>>>(w_v, Wv);
    cvt_f32_bf16<<<dim3(WSZ / 2048), blk, 0, stream>>>(w_o, Wo);

    dim3 gg(D_MODEL / 128, MROWS / 128);          // (8, 64)
    gemm_bf16<1><<<gg, blk, 0, stream>>>(Qc, Wq, b_q, Qb, 0.125f * LOG2E);
    gemm_bf16<1><<<gg, blk, 0, stream>>>(Kc, Wk, b_k, Kb, 1.0f);
    gemm_bf16<1><<<gg, blk, 0, stream>>>(Vc, Wv, b_v, Vb, 1.0f);

    transpose_v<<<dim3(SEQ / 64, BATCH * NHEADS), blk, 0, stream>>>(Vb, Vt);

    attn_mfma<<<dim3(SEQ / 128, BATCH * NHEADS), blk, 0, stream>>>(Qb, Kb, Vt, Ab);

    gemm_bf16<0><<<gg, blk, 0, stream>>>(Ab, Wo, b_o, out, 1.0f);
}

// Round 4
// 249.928 us; speedup vs baseline: 11.9915x; 1.1927x over previous
//
#include <hip/hip_runtime.h>
#include <hip/hip_bf16.h>

#define D_MODEL 1024
#define NHEADS 16
#define DKH 64
#define BATCH 4
#define SEQ 2048
#define MROWS (BATCH*SEQ)                 // 8192
#define BSD ((size_t)MROWS * D_MODEL)     // 8388608 elements
#define WSZ ((size_t)D_MODEL * D_MODEL)   // 1048576 elements
#define LOG2E 1.4426950408889634f

typedef __attribute__((ext_vector_type(8))) short   s16x8;
typedef __attribute__((ext_vector_type(8))) __bf16  bf16x8;
typedef __attribute__((ext_vector_type(4))) __bf16  bf16x4;
typedef __attribute__((ext_vector_type(4))) float   f32x4;

// XOR-swizzled LDS index for [N][64]-bf16 tiles (row stride 128B).
// scol in shorts; XOR spreads 16B chunks across banks per 8-row stripe.
#define SWZ(row, scol) ((((int)(row)) << 6) + (((int)(scol)) ^ ((((int)(row)) & 7) << 3)))

__device__ inline short f2bf(float f) {
    __bf16 h = (__bf16)f;
    short s; __builtin_memcpy(&s, &h, 2); return s;
}

__device__ inline void gl_lds16(const void* g, void* l) {
    __builtin_amdgcn_global_load_lds(
        (const __attribute__((address_space(1))) unsigned*)g,
        (__attribute__((address_space(3))) unsigned*)l, 16, 0, 0);
}

// ---------------------------------------------------------------------------
// Fused f32 -> bf16 conversion for 3 big (BSD) + 4 small (WSZ) buffers.
// Grid: 3*4096 + 4*512 = 14336 blocks.
// ---------------------------------------------------------------------------
struct CvtPtrs { const float* src[7]; short* dst[7]; };

__global__ __launch_bounds__(256) void cvt_all(CvtPtrs p)
{
    const int bx = blockIdx.x;
    int buf, boff;
    if (bx < 3 * 4096) { buf = bx >> 12; boff = bx & 4095; }
    else { const int r = bx - 3 * 4096; buf = 3 + (r >> 9); boff = r & 511; }
    const float* __restrict__ src = p.src[buf];
    short* __restrict__ dst = p.dst[buf];
    const size_t i = ((size_t)boff * 256 + threadIdx.x) * 8;
    const float4 a = *(const float4*)(src + i);
    const float4 b = *(const float4*)(src + i + 4);
    s16x8 v;
    v[0]=f2bf(a.x); v[1]=f2bf(a.y); v[2]=f2bf(a.z); v[3]=f2bf(a.w);
    v[4]=f2bf(b.x); v[5]=f2bf(b.y); v[6]=f2bf(b.z); v[7]=f2bf(b.w);
    *(s16x8*)(dst + i) = v;
}

// ---------------------------------------------------------------------------
// GEMM (bf16 in): C[m,n] = sum_k A[m,k]*W[n,k] + bias[n]
// m97 structure: 128x128 tile, BK=64, global_load_lds width 16, linear LDS.
// OMODE 1: bf16 out, head-split (B,H,S,DKH), scaled. OMODE 0: fp32 flat out.
// ---------------------------------------------------------------------------
template<int OMODE>
__global__ __launch_bounds__(256, 2) void gemm_bf16(
    const short* __restrict__ A, const short* __restrict__ W,
    const float* __restrict__ bias, void* __restrict__ Cout, float scale)
{
    __shared__ __align__(16) short As[128 * 64];
    __shared__ __align__(16) short Bs[128 * 64];
    const int t   = threadIdx.x;
    const int l   = t & 63;
    const int wid = t >> 6;
    const int g   = l >> 4, r16 = l & 15;
    const int wm  = wid >> 1, wn = wid & 1;
    const int m0  = blockIdx.y * 128, n0 = blockIdx.x * 128;
    const int srow = t >> 3;          // 0..31
    const int scol = (t & 7) * 8;     // element offset within BK=64

    f32x4 acc[4][4];
    #pragma unroll
    for (int mi = 0; mi < 4; ++mi)
        #pragma unroll
        for (int ni = 0; ni < 4; ++ni)
            acc[mi][ni] = (f32x4)0.0f;

    const short* Ap = A + (size_t)(m0 + srow) * D_MODEL + scol;
    const short* Wp = W + (size_t)(n0 + srow) * D_MODEL + scol;
    short* AsW = As + wid * 512;   // wave-uniform LDS base (lane*16B added by HW)
    short* BsW = Bs + wid * 512;

    for (int k0 = 0; k0 < D_MODEL; k0 += 64) {
        #pragma unroll
        for (int p = 0; p < 4; ++p) {
            gl_lds16(Ap + (size_t)p * 32 * D_MODEL + k0, AsW + p * 2048);
            gl_lds16(Wp + (size_t)p * 32 * D_MODEL + k0, BsW + p * 2048);
        }
        __syncthreads();
        #pragma unroll
        for (int kc = 0; kc < 2; ++kc) {
            bf16x8 a[4], b[4];
            #pragma unroll
            for (int mi = 0; mi < 4; ++mi)
                a[mi] = *(const bf16x8*)&As[(wm * 64 + mi * 16 + r16) * 64 + kc * 32 + g * 8];
            #pragma unroll
            for (int ni = 0; ni < 4; ++ni)
                b[ni] = *(const bf16x8*)&Bs[(wn * 64 + ni * 16 + r16) * 64 + kc * 32 + g * 8];
            #pragma unroll
            for (int mi = 0; mi < 4; ++mi)
                #pragma unroll
                for (int ni = 0; ni < 4; ++ni)
                    acc[mi][ni] = __builtin_amdgcn_mfma_f32_16x16x32_bf16(a[mi], b[ni], acc[mi][ni], 0, 0, 0);
        }
        __syncthreads();
    }

    #pragma unroll
    for (int mi = 0; mi < 4; ++mi)
        #pragma unroll
        for (int ni = 0; ni < 4; ++ni)
            #pragma unroll
            for (int j = 0; j < 4; ++j) {
                const int m = m0 + wm * 64 + mi * 16 + g * 4 + j;
                const int n = n0 + wn * 64 + ni * 16 + r16;
                float v = acc[mi][ni][j] + bias[n];
                if (OMODE == 1) {
                    v *= scale;
                    const size_t idx = (((size_t)((m >> 11) * NHEADS + (n >> 6)) << 11)
                                        + (size_t)(m & 2047)) * DKH + (n & 63);
                    ((short*)Cout)[idx] = f2bf(v);
                } else {
                    ((float*)Cout)[(size_t)m * D_MODEL + n] = v;
                }
            }
}

// ---------------------------------------------------------------------------
// V transpose: (BH, S, 64) bf16 -> (BH, 64, S) bf16
// ---------------------------------------------------------------------------
__global__ __launch_bounds__(256) void transpose_v(
    const short* __restrict__ Vb, short* __restrict__ Vt)
{
    __shared__ __align__(16) short T[64][72];
    const int t  = threadIdx.x;
    const int bh = blockIdx.y;
    const int s0 = blockIdx.x * 64;
    const int row = t >> 2, cb = (t & 3) * 16;
    const short* src = Vb + ((size_t)bh * SEQ + s0 + row) * DKH + cb;
    *(s16x8*)&T[row][cb]     = *(const s16x8*)(src);
    *(s16x8*)&T[row][cb + 8] = *(const s16x8*)(src + 8);
    __syncthreads();
    const int d = t >> 2, sb = (t & 3) * 16;
    s16x8 o0, o1;
    #pragma unroll
    for (int j = 0; j < 8; ++j) { o0[j] = T[sb + j][d]; o1[j] = T[sb + 8 + j][d]; }
    short* dst = Vt + ((size_t)bh * DKH + d) * SEQ + s0 + sb;
    *(s16x8*)(dst)     = o0;
    *(s16x8*)(dst + 8) = o1;
}

// ---------------------------------------------------------------------------
// Flash attention, swapped-operand MFMA, XOR-swizzled LDS, P overlaid on Q.
// Q pre-scaled by 0.125*log2(e) (exp2 domain). S^T = mfma(K,Q); O^T = mfma(Vt,P).
// Block: 4 waves x 32 q = 128 q-rows; KV tile 64. LDS = 32 KB -> 5 blocks/CU.
// ---------------------------------------------------------------------------
__global__ __launch_bounds__(256, 4) void attn_mfma(
    const short* __restrict__ Qg, const short* __restrict__ Kg,
    const short* __restrict__ Vtg, short* __restrict__ Ab)
{
    __shared__ __align__(16) short QPs[128 * 64];  // Q tile; reused as P after hoist
    __shared__ __align__(16) short Ks[64 * 64];
    __shared__ __align__(16) short Vts[64 * 64];
    const int t   = threadIdx.x;
    const int l   = t & 63;
    const int wid = t >> 6;
    const int g   = l >> 4, r16 = l & 15;
    const int bh  = blockIdx.y, b = bh >> 4, h = bh & 15;
    const int q0  = blockIdx.x * 128;
    const int wq0 = wid * 32;
    const int srow = t >> 3, scol = (t & 7) * 8;   // Q staging
    const int kr = t >> 2, kcb = (t & 3) * 16;     // K/V staging

    // stage Q tile (128 x 64), swizzled
    #pragma unroll
    for (int p = 0; p < 4; ++p) {
        const int row = srow + p * 32;
        *(s16x8*)&QPs[SWZ(row, scol)] =
            *(const s16x8*)&Qg[((size_t)bh * SEQ + q0 + row) * DKH + scol];
    }
    const short* Kbase = Kg  + (size_t)bh * SEQ * DKH;
    const short* Vbase = Vtg + (size_t)bh * DKH * SEQ;
    // prefetch KV tile 0 into registers (T14)
    s16x8 kpf0 = *(const s16x8*)&Kbase[(size_t)kr * DKH + kcb];
    s16x8 kpf1 = *(const s16x8*)&Kbase[(size_t)kr * DKH + kcb + 8];
    s16x8 vpf0 = *(const s16x8*)&Vbase[(size_t)kr * SEQ + kcb];
    s16x8 vpf1 = *(const s16x8*)&Vbase[(size_t)kr * SEQ + kcb + 8];
    __syncthreads();

    // hoist Q fragments (B-operand: lane holds col q = wq0+mi*16+r16); Qs LDS dies here
    bf16x8 bq[2][2];
    #pragma unroll
    for (int mi = 0; mi < 2; ++mi)
        #pragma unroll
        for (int kc = 0; kc < 2; ++kc)
            bq[mi][kc] = *(const bf16x8*)&QPs[SWZ(wq0 + mi * 16 + r16, kc * 32 + g * 8)];

    f32x4 o_acc[4][2];                 // [nd][mi]: O^T rows d, cols q
    float m_r[2] = {-1e30f, -1e30f};
    float l_r[2] = {0.0f, 0.0f};       // per-lane partial; reduced in epilogue
    #pragma unroll
    for (int nd = 0; nd < 4; ++nd)
        #pragma unroll
        for (int mi = 0; mi < 2; ++mi) o_acc[nd][mi] = (f32x4)0.0f;

    for (int kt = 0; kt < SEQ / 64; ++kt) {
        __syncthreads();               // all waves done reading previous K/V (and P)
        *(s16x8*)&Ks[SWZ(kr, kcb)]      = kpf0;
        *(s16x8*)&Ks[SWZ(kr, kcb + 8)]  = kpf1;
        *(s16x8*)&Vts[SWZ(kr, kcb)]     = vpf0;
        *(s16x8*)&Vts[SWZ(kr, kcb + 8)] = vpf1;
        __syncthreads();
        if (kt + 1 < SEQ / 64) {       // issue next-tile loads; land during compute
            kpf0 = *(const s16x8*)&Kbase[(size_t)((kt + 1) * 64 + kr) * DKH + kcb];
            kpf1 = *(const s16x8*)&Kbase[(size_t)((kt + 1) * 64 + kr) * DKH + kcb + 8];
            vpf0 = *(const s16x8*)&Vbase[(size_t)kr * SEQ + (kt + 1) * 64 + kcb];
            vpf1 = *(const s16x8*)&Vbase[(size_t)kr * SEQ + (kt + 1) * 64 + kcb + 8];
        }

        // S^T = K Q^T  (rows k = nk*16+g*4+j, col q = mi*16+r16)
        f32x4 sT[4][2];
        #pragma unroll
        for (int nk = 0; nk < 4; ++nk)
            #pragma unroll
            for (int mi = 0; mi < 2; ++mi) sT[nk][mi] = (f32x4)0.0f;
        #pragma unroll
        for (int kc = 0; kc < 2; ++kc) {
            bf16x8 ak[4];
            #pragma unroll
            for (int nk = 0; nk < 4; ++nk)
                ak[nk] = *(const bf16x8*)&Ks[SWZ(nk * 16 + r16, kc * 32 + g * 8)];
            #pragma unroll
            for (int nk = 0; nk < 4; ++nk)
                #pragma unroll
                for (int mi = 0; mi < 2; ++mi)
                    sT[nk][mi] = __builtin_amdgcn_mfma_f32_16x16x32_bf16(ak[nk], bq[mi][kc], sT[nk][mi], 0, 0, 0);
        }

        // lane-local online softmax (exp2 domain), defer-max THR=8
        #pragma unroll
        for (int mi = 0; mi < 2; ++mi) {
            float mx = -1e30f;
            #pragma unroll
            for (int nk = 0; nk < 4; ++nk)
                #pragma unroll
                for (int j = 0; j < 4; ++j) mx = fmaxf(mx, sT[nk][mi][j]);
            mx = fmaxf(mx, __shfl_xor(mx, 16));
            mx = fmaxf(mx, __shfl_xor(mx, 32));
            if (__any(mx > m_r[mi] + 8.0f)) {
                const float mnew = fmaxf(m_r[mi], mx);
                const float resc = __builtin_amdgcn_exp2f(m_r[mi] - mnew);
                m_r[mi] = mnew;
                l_r[mi] *= resc;
                #pragma unroll
                for (int nd = 0; nd < 4; ++nd)
                    #pragma unroll
                    for (int j = 0; j < 4; ++j) o_acc[nd][mi][j] *= resc;
            }
            float sum = 0.0f;
            #pragma unroll
            for (int nk = 0; nk < 4; ++nk)
                #pragma unroll
                for (int j = 0; j < 4; ++j) {
                    const float pv = __builtin_amdgcn_exp2f(sT[nk][mi][j] - m_r[mi]);
                    sT[nk][mi][j] = pv;
                    sum += pv;
                }
            l_r[mi] += sum;
        }

        // publish P[q][k] bf16 into per-wave region of QPs (8B packed, swizzled)
        #pragma unroll
        for (int mi = 0; mi < 2; ++mi)
            #pragma unroll
            for (int nk = 0; nk < 4; ++nk) {
                bf16x4 pk;
                pk[0] = (__bf16)sT[nk][mi][0]; pk[1] = (__bf16)sT[nk][mi][1];
                pk[2] = (__bf16)sT[nk][mi][2]; pk[3] = (__bf16)sT[nk][mi][3];
                *(bf16x4*)&QPs[SWZ(wq0 + mi * 16 + r16, nk * 16 + g * 4)] = pk;
            }

        // O^T += V^T P^T  (A = V^T rows d, B = P^T cols q)
        #pragma unroll
        for (int kc = 0; kc < 2; ++kc) {
            bf16x8 av[4], bp[2];
            #pragma unroll
            for (int nd = 0; nd < 4; ++nd)
                av[nd] = *(const bf16x8*)&Vts[SWZ(nd * 16 + r16, kc * 32 + g * 8)];
            #pragma unroll
            for (int mi = 0; mi < 2; ++mi)
                bp[mi] = *(const bf16x8*)&QPs[SWZ(wq0 + mi * 16 + r16, kc * 32 + g * 8)];
            #pragma unroll
            for (int nd = 0; nd < 4; ++nd)
                #pragma unroll
                for (int mi = 0; mi < 2; ++mi)
                    o_acc[nd][mi] = __builtin_amdgcn_mfma_f32_16x16x32_bf16(av[nd], bp[mi], o_acc[nd][mi], 0, 0, 0);
        }
    }

    // epilogue: reduce l across g-lanes, normalize, write O (B,S,D) bf16
    #pragma unroll
    for (int mi = 0; mi < 2; ++mi) {
        float lt = l_r[mi];
        lt += __shfl_xor(lt, 16);
        lt += __shfl_xor(lt, 32);
        const float inv = 1.0f / lt;
        const int q = q0 + wq0 + mi * 16 + r16;
        short* Op = Ab + ((size_t)b * SEQ + q) * D_MODEL + h * DKH;
        #pragma unroll
        for (int nd = 0; nd < 4; ++nd) {
            bf16x4 ov;
            ov[0] = (__bf16)(o_acc[nd][mi][0] * inv);
            ov[1] = (__bf16)(o_acc[nd][mi][1] * inv);
            ov[2] = (__bf16)(o_acc[nd][mi][2] * inv);
            ov[3] = (__bf16)(o_acc[nd][mi][3] * inv);
            *(bf16x4*)&Op[nd * 16 + g * 4] = ov;
        }
    }
}

extern "C" void kernel_launch(void* const* d_in, const int* in_sizes, int n_in,
                              void* d_out, int out_size, void* d_ws, size_t ws_size,
                              hipStream_t stream) {
    const float* q_in = (const float*)d_in[0];
    const float* k_in = (const float*)d_in[1];
    const float* v_in = (const float*)d_in[2];
    const float* w_q  = (const float*)d_in[3];
    const float* b_q  = (const float*)d_in[4];
    const float* w_k  = (const float*)d_in[5];
    const float* b_k  = (const float*)d_in[6];
    const float* w_v  = (const float*)d_in[7];
    const float* b_v  = (const float*)d_in[8];
    const float* w_o  = (const float*)d_in[9];
    const float* b_o  = (const float*)d_in[10];
    float* out = (float*)d_out;

    short* ws = (short*)d_ws;
    short* Qc  = ws;                          // bf16 copies of inputs
    short* Kc  = ws + BSD;
    short* Vc  = ws + 2 * BSD;
    short* Wq  = ws + 3 * BSD;
    short* Wk  = Wq + WSZ;
    short* Wv  = Wk + WSZ;
    short* Wo  = Wv + WSZ;
    short* Qb  = ws + 3 * BSD + 4 * WSZ;      // (B*H,S,64) bf16, scaled
    short* Kb  = Qb + BSD;
    short* Vb  = Kb + BSD;
    short* Vt  = Qc;                          // alias: Qc dead after Q-proj
    short* Ab  = Kc;                          // alias: Kc dead after K-proj

    dim3 blk(256);
    CvtPtrs cp;
    cp.src[0] = q_in; cp.dst[0] = Qc;
    cp.src[1] = k_in; cp.dst[1] = Kc;
    cp.src[2] = v_in; cp.dst[2] = Vc;
    cp.src[3] = w_q;  cp.dst[3] = Wq;
    cp.src[4] = w_k;  cp.dst[4] = Wk;
    cp.src[5] = w_v;  cp.dst[5] = Wv;
    cp.src[6] = w_o;  cp.dst[6] = Wo;
    cvt_all<<<dim3(3 * 4096 + 4 * 512), blk, 0, stream>>>(cp);

    dim3 gg(D_MODEL / 128, MROWS / 128);          // (8, 64)
    gemm_bf16<1><<<gg, blk, 0, stream>>>(Qc, Wq, b_q, Qb, 0.125f * LOG2E);
    gemm_bf16<1><<<gg, blk, 0, stream>>>(Kc, Wk, b_k, Kb, 1.0f);
    gemm_bf16<1><<<gg, blk, 0, stream>>>(Vc, Wv, b_v, Vb, 1.0f);

    transpose_v<<<dim3(SEQ / 64, BATCH * NHEADS), blk, 0, stream>>>(Vb, Vt);

    attn_mfma<<<dim3(SEQ / 128, BATCH * NHEADS), blk, 0, stream>>>(Qb, Kb, Vt, Ab);

    gemm_bf16<0><<<gg, blk, 0, stream>>>(Ab, Wo, b_o, out, 1.0f);
}